// Round 1
// baseline (935.580 us; speedup 1.0000x reference)
//
#include <hip/hip_runtime.h>
#include <cstddef>

// ---------------------------------------------------------------------------
// MultigridLayer: c/r bilinear downsample + steps pair-sum + AAt (bf16 MFMA,
// symmetric, Pinv folded as sqrt into columns) + D row-weighted-sumsq.
//
// Output layout (fp32, flat):
//   c   [2][1024][6]     @ 0         (12288)
//   r   [2][1024]        @ 12288     (2048)
//   sx  [2][31]          @ 14336     (62)
//   sy  [2][31]          @ 14398     (62)
//   AAt [1][4096][4096]  @ 14460     (16777216)
//   D   [2][4096]        @ 16791676  (8192)
// ---------------------------------------------------------------------------

#define NVAR 12288
#define NN   16384   // NUM_VAR + NUM_EPS (K dim of the GEMM)
#define MM   4096    // NUM_EPS (M=N of AAt)

typedef __bf16 bf8v __attribute__((ext_vector_type(8)));
typedef float  f4v  __attribute__((ext_vector_type(4)));
typedef unsigned short u16;

__device__ __forceinline__ void gld_lds16(const void* g, void* l) {
  __builtin_amdgcn_global_load_lds((const __attribute__((address_space(1))) void*)g,
                                   (__attribute__((address_space(3))) void*)l,
                                   16, 0, 0);
}

// round-to-nearest-even fp32 -> bf16 (finite values only)
__device__ __forceinline__ u16 f2bf(float x) {
  unsigned int u = __float_as_uint(x);
  u = (u + 0x7fffu + ((u >> 16) & 1u)) >> 16;
  return (u16)u;
}

// jax.image.resize linear+antialias, scale=1/2: taps at 2i-1..2i+2, raw
// weights {.25,.75,.75,.25}, out-of-range dropped, renormalized.
__device__ __forceinline__ void make_taps(int i, float w[4], int p[4]) {
  const float rw[4] = {0.25f, 0.75f, 0.75f, 0.25f};
  float s = 0.f;
#pragma unroll
  for (int t = 0; t < 4; ++t) {
    int pp = 2 * i - 1 + t;
    bool v = (pp >= 0) && (pp < 64);
    p[t] = v ? pp : 0;
    w[t] = v ? rw[t] : 0.f;
    s += w[t];
  }
  float inv = 1.f / s;
#pragma unroll
  for (int t = 0; t < 4; ++t) w[t] *= inv;
}

// --------------------------- small outputs --------------------------------
__global__ void small_ops(const float* __restrict__ coeffs,
                          const float* __restrict__ rhs,
                          const float* __restrict__ stx,
                          const float* __restrict__ sty,
                          float* __restrict__ out) {
  int idx = blockIdx.x * 256 + threadIdx.x;
  if (idx < 12288) {                       // c: [b][pix][o]
    int b = idx / 6144, rem = idx % 6144;
    int pix = rem / 6, o = rem % 6;
    int yi = pix >> 5, xi = pix & 31;
    float wy[4], wx[4]; int py[4], px[4];
    make_taps(yi, wy, py);
    make_taps(xi, wx, px);
    float acc = 0.f;
#pragma unroll
    for (int dy = 0; dy < 4; ++dy) {
      float sx = 0.f;
#pragma unroll
      for (int dx = 0; dx < 4; ++dx)
        sx += wx[dx] * coeffs[((size_t)b * 4096 + py[dy] * 64 + px[dx]) * 6 + o];
      acc += wy[dy] * sx;
    }
    out[idx] = acc;
  } else if (idx < 14336) {                // r: [b][pix]
    int j = idx - 12288;
    int b = j >> 10, pix = j & 1023;
    int yi = pix >> 5, xi = pix & 31;
    float wy[4], wx[4]; int py[4], px[4];
    make_taps(yi, wy, py);
    make_taps(xi, wx, px);
    float acc = 0.f;
#pragma unroll
    for (int dy = 0; dy < 4; ++dy) {
      float sx = 0.f;
#pragma unroll
      for (int dx = 0; dx < 4; ++dx)
        sx += wx[dx] * rhs[(size_t)b * 4096 + py[dy] * 64 + px[dx]];
      acc += wy[dy] * sx;
    }
    out[idx] = acc;
  } else if (idx < 14460) {                // sx then sy: pair sums
    int j = idx - 14336;
    if (j < 62) {
      int b = j / 31, i = j % 31;
      out[idx] = stx[b * 63 + 2 * i] + stx[b * 63 + 2 * i + 1];
    } else {
      j -= 62;
      int b = j / 31, i = j % 31;
      out[idx] = sty[b * 63 + 2 * i] + sty[b * 63 + 2 * i + 1];
    }
  }
}

// ------------------- D + fused bf16*sqrt(Pinv) convert ---------------------
// one block per (row m, batch b); 256 threads read the 16384-float row.
__global__ __launch_bounds__(256)
void d_and_convert(const float* __restrict__ A, float* __restrict__ Dout,
                   u16* __restrict__ Abf, const int useWs) {
  const int m = blockIdx.x, b = blockIdx.y;
  const int t = threadIdx.x;
  const float PV = 1.0f / 1e-5f, PE = 1.0f / 1e5f;
  const float SV = sqrtf(PV), SE = sqrtf(PE);
  const float* __restrict__ row = A + ((size_t)b * MM + m) * NN;
  const bool wr = (b == 0) && useWs;
  float acc = 0.f;
#pragma unroll
  for (int i = 0; i < 16; ++i) {
    const int n = i * 1024 + t * 4;        // boundary 12288 = iter 12 exactly
    const float4 v = *(const float4*)(row + n);
    const bool isv = n < NVAR;
    const float pv = isv ? PV : PE;
    acc += pv * (v.x * v.x + v.y * v.y + v.z * v.z + v.w * v.w);
    if (wr) {
      const float s = isv ? SV : SE;
      ushort4 o;
      o.x = f2bf(v.x * s); o.y = f2bf(v.y * s);
      o.z = f2bf(v.z * s); o.w = f2bf(v.w * s);
      *(ushort4*)(Abf + (size_t)m * NN + n) = o;
    }
  }
#pragma unroll
  for (int off = 32; off > 0; off >>= 1) acc += __shfl_down(acc, off);
  __shared__ float red[4];
  if ((t & 63) == 0) red[t >> 6] = acc;
  __syncthreads();
  if (t == 0) Dout[(size_t)b * MM + m] = red[0] + red[1] + red[2] + red[3];
}

// ------------------------------- AAt GEMM ---------------------------------
// C = X Xt with X = bf16(A[0] * sqrt(Pinv)) [4096 x 16384].
// 128x128 tile, BK=64, 4 waves each computing a 64x64 sub-tile via
// 4x4 fragments of mfma_f32_16x16x32_bf16. Symmetric: block (bi<=bj) writes
// its tile and the mirrored tile. m97 structure (global_load_lds width 16,
// 2 barriers per K-step).
template <int USE_WS>
__global__ __launch_bounds__(256)
void gemm_aat(const u16* __restrict__ Abf, const float* __restrict__ A0,
              float* __restrict__ C) {
  const int bj = blockIdx.x, bi = blockIdx.y;
  if (bi > bj) return;
  __shared__ u16 ldsA[128 * 64];
  __shared__ u16 ldsB[128 * 64];
  const int t = threadIdx.x;
  const int lane = t & 63;
  const int wave = t >> 6;
  const int wr = (wave >> 1) * 64;   // wave's row offset in tile
  const int wc = (wave & 1) * 64;    // wave's col offset in tile

  f4v acc[4][4];
#pragma unroll
  for (int i = 0; i < 4; ++i)
#pragma unroll
    for (int j = 0; j < 4; ++j)
      acc[i][j] = f4v{0.f, 0.f, 0.f, 0.f};

  const int srow = t >> 3;           // staging row 0..31 (per 32-row chunk)
  const int scol = (t & 7) * 8;      // staging col 0..56
  const size_t rA = (size_t)bi * 128 + srow;
  const size_t rB = (size_t)bj * 128 + srow;
  const int ldse = t * 8;            // per-thread LDS elem offset in chunk

  const float SV = sqrtf(1.0f / 1e-5f);
  const float SE = sqrtf(1.0f / 1e5f);

  for (int kt = 0; kt < 256; ++kt) {
    const int kb = kt * 64;
    if (USE_WS) {
#pragma unroll
      for (int i = 0; i < 4; ++i) {
        gld_lds16(Abf + (rA + i * 32) * NN + kb + scol, &ldsA[i * 2048 + ldse]);
        gld_lds16(Abf + (rB + i * 32) * NN + kb + scol, &ldsB[i * 2048 + ldse]);
      }
    } else {
      // fallback: reg-stage fp32 -> scaled bf16 -> LDS
      const int n = kb + scol;                    // 8-chunk never crosses 12288
      const float s = (n < NVAR) ? SV : SE;
#pragma unroll
      for (int i = 0; i < 4; ++i) {
        const float* ga = A0 + (rA + i * 32) * NN + n;
        const float* gb = A0 + (rB + i * 32) * NN + n;
        const float4 a0 = ((const float4*)ga)[0], a1 = ((const float4*)ga)[1];
        const float4 b0 = ((const float4*)gb)[0], b1 = ((const float4*)gb)[1];
        u16* dA = &ldsA[i * 2048 + ldse];
        u16* dB = &ldsB[i * 2048 + ldse];
        dA[0] = f2bf(a0.x * s); dA[1] = f2bf(a0.y * s);
        dA[2] = f2bf(a0.z * s); dA[3] = f2bf(a0.w * s);
        dA[4] = f2bf(a1.x * s); dA[5] = f2bf(a1.y * s);
        dA[6] = f2bf(a1.z * s); dA[7] = f2bf(a1.w * s);
        dB[0] = f2bf(b0.x * s); dB[1] = f2bf(b0.y * s);
        dB[2] = f2bf(b0.z * s); dB[3] = f2bf(b0.w * s);
        dB[4] = f2bf(b1.x * s); dB[5] = f2bf(b1.y * s);
        dB[6] = f2bf(b1.z * s); dB[7] = f2bf(b1.w * s);
      }
    }
    __syncthreads();
#pragma unroll
    for (int kk = 0; kk < 2; ++kk) {
      bf8v af[4], bfr[4];
#pragma unroll
      for (int i = 0; i < 4; ++i)
        af[i] = *(const bf8v*)&ldsA[(wr + i * 16 + (lane & 15)) * 64 +
                                    kk * 32 + (lane >> 4) * 8];
#pragma unroll
      for (int j = 0; j < 4; ++j)
        bfr[j] = *(const bf8v*)&ldsB[(wc + j * 16 + (lane & 15)) * 64 +
                                     kk * 32 + (lane >> 4) * 8];
#pragma unroll
      for (int i = 0; i < 4; ++i)
#pragma unroll
        for (int j = 0; j < 4; ++j)
          acc[i][j] = __builtin_amdgcn_mfma_f32_16x16x32_bf16(
              af[i], bfr[j], acc[i][j], 0, 0, 0);
    }
    __syncthreads();
  }

  // epilogue: C/D layout col=lane&15, row=(lane>>4)*4+reg
  const int cc = lane & 15;
  const int cr = (lane >> 4) * 4;
#pragma unroll
  for (int i = 0; i < 4; ++i)
#pragma unroll
    for (int j = 0; j < 4; ++j)
#pragma unroll
      for (int r = 0; r < 4; ++r) {
        const int gr = bi * 128 + wr + i * 16 + cr + r;
        const int gc = bj * 128 + wc + j * 16 + cc;
        C[(size_t)gr * MM + gc] = acc[i][j][r];
      }
  if (bi != bj) {
#pragma unroll
    for (int i = 0; i < 4; ++i)
#pragma unroll
      for (int j = 0; j < 4; ++j)
#pragma unroll
        for (int r = 0; r < 4; ++r) {
          const int gr = bi * 128 + wr + i * 16 + cr + r;
          const int gc = bj * 128 + wc + j * 16 + cc;
          C[(size_t)gc * MM + gr] = acc[i][j][r];
        }
  }
}

// ------------------------------- launch ------------------------------------
extern "C" void kernel_launch(void* const* d_in, const int* in_sizes, int n_in,
                              void* d_out, int out_size, void* d_ws,
                              size_t ws_size, hipStream_t stream) {
  const float* coeffs = (const float*)d_in[0];
  const float* rhs    = (const float*)d_in[1];
  const float* stx    = (const float*)d_in[2];
  const float* sty    = (const float*)d_in[3];
  const float* A      = (const float*)d_in[4];

  float* out    = (float*)d_out;
  float* outAAt = out + 14460;
  float* outD   = out + 16791676;

  const size_t need = (size_t)MM * NN * sizeof(u16);  // 128 MiB
  const int useWs = (ws_size >= need) ? 1 : 0;
  u16* Abf = (u16*)d_ws;

  small_ops<<<dim3(57), dim3(256), 0, stream>>>(coeffs, rhs, stx, sty, out);
  d_and_convert<<<dim3(MM, 2), dim3(256), 0, stream>>>(A, outD, Abf, useWs);
  if (useWs)
    gemm_aat<1><<<dim3(32, 32), dim3(256), 0, stream>>>(Abf, A, outAAt);
  else
    gemm_aat<0><<<dim3(32, 32), dim3(256), 0, stream>>>(Abf, A, outAAt);
}

// Round 2
// 571.131 us; speedup vs baseline: 1.6381x; 1.6381x over previous
//
#include <hip/hip_runtime.h>
#include <cstddef>

// ---------------------------------------------------------------------------
// MultigridLayer: c/r bilinear downsample + steps pair-sum + AAt (bf16 MFMA,
// symmetric, Pinv folded as sqrt into columns) + D row-weighted-sumsq.
//
// Output layout (fp32, flat):
//   c   [2][1024][6]     @ 0         (12288)
//   r   [2][1024]        @ 12288     (2048)
//   sx  [2][31]          @ 14336     (62)
//   sy  [2][31]          @ 14398     (62)
//   AAt [1][4096][4096]  @ 14460     (16777216)
//   D   [2][4096]        @ 16791676  (8192)
// ---------------------------------------------------------------------------

#define NVAR 12288
#define NN   16384   // NUM_VAR + NUM_EPS (K dim of the GEMM)
#define MM   4096    // NUM_EPS (M=N of AAt)

typedef __bf16 bf8v __attribute__((ext_vector_type(8)));
typedef float  f4v  __attribute__((ext_vector_type(4)));
typedef unsigned short u16;

__device__ __forceinline__ void gld_lds16(const void* g, void* l) {
  __builtin_amdgcn_global_load_lds((const __attribute__((address_space(1))) void*)g,
                                   (__attribute__((address_space(3))) void*)l,
                                   16, 0, 0);
}

// round-to-nearest-even fp32 -> bf16 (finite values only)
__device__ __forceinline__ u16 f2bf(float x) {
  unsigned int u = __float_as_uint(x);
  u = (u + 0x7fffu + ((u >> 16) & 1u)) >> 16;
  return (u16)u;
}

// jax.image.resize linear+antialias, scale=1/2: taps at 2i-1..2i+2, raw
// weights {.25,.75,.75,.25}, out-of-range dropped, renormalized.
__device__ __forceinline__ void make_taps(int i, float w[4], int p[4]) {
  const float rw[4] = {0.25f, 0.75f, 0.75f, 0.25f};
  float s = 0.f;
#pragma unroll
  for (int t = 0; t < 4; ++t) {
    int pp = 2 * i - 1 + t;
    bool v = (pp >= 0) && (pp < 64);
    p[t] = v ? pp : 0;
    w[t] = v ? rw[t] : 0.f;
    s += w[t];
  }
  float inv = 1.f / s;
#pragma unroll
  for (int t = 0; t < 4; ++t) w[t] *= inv;
}

// --------------------------- small outputs --------------------------------
__global__ void small_ops(const float* __restrict__ coeffs,
                          const float* __restrict__ rhs,
                          const float* __restrict__ stx,
                          const float* __restrict__ sty,
                          float* __restrict__ out) {
  int idx = blockIdx.x * 256 + threadIdx.x;
  if (idx < 12288) {                       // c: [b][pix][o]
    int b = idx / 6144, rem = idx % 6144;
    int pix = rem / 6, o = rem % 6;
    int yi = pix >> 5, xi = pix & 31;
    float wy[4], wx[4]; int py[4], px[4];
    make_taps(yi, wy, py);
    make_taps(xi, wx, px);
    float acc = 0.f;
#pragma unroll
    for (int dy = 0; dy < 4; ++dy) {
      float sx = 0.f;
#pragma unroll
      for (int dx = 0; dx < 4; ++dx)
        sx += wx[dx] * coeffs[((size_t)b * 4096 + py[dy] * 64 + px[dx]) * 6 + o];
      acc += wy[dy] * sx;
    }
    out[idx] = acc;
  } else if (idx < 14336) {                // r: [b][pix]
    int j = idx - 12288;
    int b = j >> 10, pix = j & 1023;
    int yi = pix >> 5, xi = pix & 31;
    float wy[4], wx[4]; int py[4], px[4];
    make_taps(yi, wy, py);
    make_taps(xi, wx, px);
    float acc = 0.f;
#pragma unroll
    for (int dy = 0; dy < 4; ++dy) {
      float sx = 0.f;
#pragma unroll
      for (int dx = 0; dx < 4; ++dx)
        sx += wx[dx] * rhs[(size_t)b * 4096 + py[dy] * 64 + px[dx]];
      acc += wy[dy] * sx;
    }
    out[idx] = acc;
  } else if (idx < 14460) {                // sx then sy: pair sums
    int j = idx - 14336;
    if (j < 62) {
      int b = j / 31, i = j % 31;
      out[idx] = stx[b * 63 + 2 * i] + stx[b * 63 + 2 * i + 1];
    } else {
      j -= 62;
      int b = j / 31, i = j % 31;
      out[idx] = sty[b * 63 + 2 * i] + sty[b * 63 + 2 * i + 1];
    }
  }
}

// ------------------- D + fused bf16*sqrt(Pinv) convert ---------------------
// one block per (row m, batch b); 256 threads read the 16384-float row.
__global__ __launch_bounds__(256)
void d_and_convert(const float* __restrict__ A, float* __restrict__ Dout,
                   u16* __restrict__ Abf, const int useWs) {
  const int m = blockIdx.x, b = blockIdx.y;
  const int t = threadIdx.x;
  const float PV = 1.0f / 1e-5f, PE = 1.0f / 1e5f;
  const float SV = sqrtf(PV), SE = sqrtf(PE);
  const float* __restrict__ row = A + ((size_t)b * MM + m) * NN;
  const bool wr = (b == 0) && useWs;
  float acc = 0.f;
#pragma unroll
  for (int i = 0; i < 16; ++i) {
    const int n = i * 1024 + t * 4;        // boundary 12288 = iter 12 exactly
    const float4 v = *(const float4*)(row + n);
    const bool isv = n < NVAR;
    const float pv = isv ? PV : PE;
    acc += pv * (v.x * v.x + v.y * v.y + v.z * v.z + v.w * v.w);
    if (wr) {
      const float s = isv ? SV : SE;
      ushort4 o;
      o.x = f2bf(v.x * s); o.y = f2bf(v.y * s);
      o.z = f2bf(v.z * s); o.w = f2bf(v.w * s);
      *(ushort4*)(Abf + (size_t)m * NN + n) = o;
    }
  }
#pragma unroll
  for (int off = 32; off > 0; off >>= 1) acc += __shfl_down(acc, off);
  __shared__ float red[4];
  if ((t & 63) == 0) red[t >> 6] = acc;
  __syncthreads();
  if (t == 0) Dout[(size_t)b * MM + m] = red[0] + red[1] + red[2] + red[3];
}

// ------------------------------- AAt GEMM ---------------------------------
// C = X Xt with X = bf16(A[0] * sqrt(Pinv)) [4096 x 16384].
// 128x128 tile, BK=64, 4 waves each computing a 64x64 sub-tile via
// 4x4 fragments of mfma_f32_16x16x32_bf16. Triangular grid (528 blocks,
// bi<=bj decoded from linear id, XCD-swizzled). T2 bank-conflict fix:
// LDS column-chunk XOR swizzle applied on the GLOBAL source address
// (global_load_lds writes linearly) and on the ds_read address.
template <int USE_WS>
__global__ __launch_bounds__(256)
void gemm_aat(const u16* __restrict__ Abf, const float* __restrict__ A0,
              float* __restrict__ C) {
  // ---- XCD swizzle (528 % 8 == 0 -> simple remap is bijective) ----
  const int k0 = blockIdx.x;
  const int kid = (k0 & 7) * 66 + (k0 >> 3);
  // ---- triangular decode: S(i) = (65*i - i*i)/2, bi s.t. S(bi)<=kid ----
  int bi = (int)((65.0f - sqrtf(65.0f * 65.0f - 8.0f * (float)kid)) * 0.5f);
  while (((65 * (bi + 1) - (bi + 1) * (bi + 1)) >> 1) <= kid) ++bi;
  while (((65 * bi - bi * bi) >> 1) > kid) --bi;
  const int bj = bi + (kid - ((65 * bi - bi * bi) >> 1));

  __shared__ u16 ldsA[128 * 64];
  __shared__ u16 ldsB[128 * 64];
  const int t = threadIdx.x;
  const int lane = t & 63;
  const int wave = t >> 6;
  const int wr = (wave >> 1) * 64;   // wave's row offset in tile
  const int wc = (wave & 1) * 64;    // wave's col offset in tile

  f4v acc[4][4];
#pragma unroll
  for (int i = 0; i < 4; ++i)
#pragma unroll
    for (int j = 0; j < 4; ++j)
      acc[i][j] = f4v{0.f, 0.f, 0.f, 0.f};

  // staging: thread t fills LDS row (t>>3), 16B chunk (t&7) of each 32-row
  // block; source column chunk is XOR-swizzled so that
  // LDS[row][c] = global[row][c ^ (row&7)]  (chunks of 8 elems / 16B)
  const int srow = t >> 3;
  const int scol = (((t & 7) ^ (srow & 7)) * 8);   // swizzled source chunk
  const size_t rA = (size_t)bi * 128 + srow;
  const size_t rB = (size_t)bj * 128 + srow;
  const int ldse = t * 8;            // linear per-thread LDS elem offset

  const float SV = sqrtf(1.0f / 1e-5f);
  const float SE = sqrtf(1.0f / 1e5f);

  // ds_read swizzle: row ra, chunk (kk*4+q) -> chunk ^ (ra&7); ra&7 == p&7
  const int q = lane >> 4;
  const int p = lane & 15;
  const int csw0 = ((0 * 4 + q) ^ (p & 7)) * 8;    // kk=0 chunk offset (elems)
  const int csw1 = ((1 * 4 + q) ^ (p & 7)) * 8;    // kk=1

  for (int kt = 0; kt < 256; ++kt) {
    const int kb = kt * 64;
    if (USE_WS) {
#pragma unroll
      for (int i = 0; i < 4; ++i) {
        gld_lds16(Abf + (rA + i * 32) * NN + kb + scol, &ldsA[i * 2048 + ldse]);
        gld_lds16(Abf + (rB + i * 32) * NN + kb + scol, &ldsB[i * 2048 + ldse]);
      }
    } else {
      // fallback: reg-stage fp32 -> scaled bf16 -> LDS (same swizzle)
      const int n = kb + scol;                    // 8-chunk never crosses 12288
      const float s = (n < NVAR) ? SV : SE;
#pragma unroll
      for (int i = 0; i < 4; ++i) {
        const float* ga = A0 + (rA + i * 32) * NN + n;
        const float* gb = A0 + (rB + i * 32) * NN + n;
        const float4 a0 = ((const float4*)ga)[0], a1 = ((const float4*)ga)[1];
        const float4 b0 = ((const float4*)gb)[0], b1 = ((const float4*)gb)[1];
        u16* dA = &ldsA[i * 2048 + ldse];
        u16* dB = &ldsB[i * 2048 + ldse];
        dA[0] = f2bf(a0.x * s); dA[1] = f2bf(a0.y * s);
        dA[2] = f2bf(a0.z * s); dA[3] = f2bf(a0.w * s);
        dA[4] = f2bf(a1.x * s); dA[5] = f2bf(a1.y * s);
        dA[6] = f2bf(a1.z * s); dA[7] = f2bf(a1.w * s);
        dB[0] = f2bf(b0.x * s); dB[1] = f2bf(b0.y * s);
        dB[2] = f2bf(b0.z * s); dB[3] = f2bf(b0.w * s);
        dB[4] = f2bf(b1.x * s); dB[5] = f2bf(b1.y * s);
        dB[6] = f2bf(b1.z * s); dB[7] = f2bf(b1.w * s);
      }
    }
    __syncthreads();
#pragma unroll
    for (int kk = 0; kk < 2; ++kk) {
      const int co = kk ? csw1 : csw0;
      bf8v af[4], bfr[4];
#pragma unroll
      for (int i = 0; i < 4; ++i)
        af[i] = *(const bf8v*)&ldsA[(wr + i * 16 + p) * 64 + co];
#pragma unroll
      for (int j = 0; j < 4; ++j)
        bfr[j] = *(const bf8v*)&ldsB[(wc + j * 16 + p) * 64 + co];
#pragma unroll
      for (int i = 0; i < 4; ++i)
#pragma unroll
        for (int j = 0; j < 4; ++j)
          acc[i][j] = __builtin_amdgcn_mfma_f32_16x16x32_bf16(
              af[i], bfr[j], acc[i][j], 0, 0, 0);
    }
    __syncthreads();
  }

  // epilogue: C/D layout col=lane&15, row=(lane>>4)*4+reg
  const int cc = p;
  const int cr = q * 4;
#pragma unroll
  for (int i = 0; i < 4; ++i)
#pragma unroll
    for (int j = 0; j < 4; ++j)
#pragma unroll
      for (int r = 0; r < 4; ++r) {
        const int gr = bi * 128 + wr + i * 16 + cr + r;
        const int gc = bj * 128 + wc + j * 16 + cc;
        C[(size_t)gr * MM + gc] = acc[i][j][r];
      }
  if (bi != bj) {
#pragma unroll
    for (int i = 0; i < 4; ++i)
#pragma unroll
      for (int j = 0; j < 4; ++j)
#pragma unroll
        for (int r = 0; r < 4; ++r) {
          const int gr = bi * 128 + wr + i * 16 + cr + r;
          const int gc = bj * 128 + wc + j * 16 + cc;
          C[(size_t)gc * MM + gr] = acc[i][j][r];
        }
  }
}

// ------------------------------- launch ------------------------------------
extern "C" void kernel_launch(void* const* d_in, const int* in_sizes, int n_in,
                              void* d_out, int out_size, void* d_ws,
                              size_t ws_size, hipStream_t stream) {
  const float* coeffs = (const float*)d_in[0];
  const float* rhs    = (const float*)d_in[1];
  const float* stx    = (const float*)d_in[2];
  const float* sty    = (const float*)d_in[3];
  const float* A      = (const float*)d_in[4];

  float* out    = (float*)d_out;
  float* outAAt = out + 14460;
  float* outD   = out + 16791676;

  const size_t need = (size_t)MM * NN * sizeof(u16);  // 128 MiB
  const int useWs = (ws_size >= need) ? 1 : 0;
  u16* Abf = (u16*)d_ws;

  small_ops<<<dim3(57), dim3(256), 0, stream>>>(coeffs, rhs, stx, sty, out);
  d_and_convert<<<dim3(MM, 2), dim3(256), 0, stream>>>(A, outD, Abf, useWs);
  if (useWs)
    gemm_aat<1><<<dim3(528), dim3(256), 0, stream>>>(Abf, A, outAAt);
  else
    gemm_aat<0><<<dim3(528), dim3(256), 0, stream>>>(Abf, A, outAAt);
}